// Round 8
// baseline (5341.360 us; speedup 1.0000x reference)
//
#include <hip/hip_runtime.h>
#include <math.h>

#define B_ 8
#define S_ 256
#define H_ 768
#define NL_ 12
#define NH_ 12
#define DH_ 64
#define FF_ 3072
#define NT_ 9
#define TLEN_ 254
#define NEG_ -10000.0f
#define TOK_ (B_ * S_)   // 2048

typedef __bf16 bf16x8 __attribute__((ext_vector_type(8)));
typedef float  f32x4  __attribute__((ext_vector_type(4)));
typedef unsigned short u16x8 __attribute__((ext_vector_type(8)));

// Offsets of transposed weights inside the wthi/wtlo buffers (elements)
#define OFF_Q 0L
#define OFF_K 589824L
#define OFF_V 1179648L
#define OFF_O 1769472L
#define OFF_1 2359296L
#define OFF_2 4718592L
#define WTOT_ 7077888L

// ---------------------------------------------------------------------------
// bf16 split helpers: f ≈ hi + lo with hi,lo bf16 (RNE). Error ~2^-17 rel.
// ---------------------------------------------------------------------------
__device__ __forceinline__ unsigned short bf16_rne(float f) {
    unsigned int u = __float_as_uint(f);
    unsigned int r = u + 0x7FFFu + ((u >> 16) & 1u);
    return (unsigned short)(r >> 16);
}
__device__ __forceinline__ void split_bf16(float f, unsigned short& h, unsigned short& l) {
    h = bf16_rne(f);
    const float hf = __uint_as_float((unsigned int)h << 16);
    l = bf16_rne(f - hf);
}

// ---------------------------------------------------------------------------
// Block-wide sum+sumsq reduction (256 threads)
// ---------------------------------------------------------------------------
__device__ __forceinline__ void block_reduce2(float& sum, float& ssq) {
    #pragma unroll
    for (int off = 32; off; off >>= 1) {
        sum += __shfl_down(sum, off);
        ssq += __shfl_down(ssq, off);
    }
    __shared__ float rs[4], rq[4];
    const int w = threadIdx.x >> 6;
    if ((threadIdx.x & 63) == 0) { rs[w] = sum; rq[w] = ssq; }
    __syncthreads();
    sum = rs[0] + rs[1] + rs[2] + rs[3];
    ssq = rq[0] + rq[1] + rq[2] + rq[3];
}

// ---------------------------------------------------------------------------
// Embedding gather + LayerNorm; writes fp32 x AND hi/lo bf16 (GEMM A operand)
// ---------------------------------------------------------------------------
__global__ __launch_bounds__(256) void embed_ln_kernel(
        const int* __restrict__ sent, const float* __restrict__ we,
        const float* __restrict__ pe, const float* __restrict__ te,
        const float* __restrict__ g, const float* __restrict__ bb,
        float* __restrict__ out, unsigned short* __restrict__ ohi,
        unsigned short* __restrict__ olo) {
    const int row = blockIdx.x;
    const int s   = row & (S_ - 1);
    const int tid = threadIdx.x;
    const int id  = sent[row];
    float v[3];
    #pragma unroll
    for (int u = 0; u < 3; ++u) {
        const int i = tid + u * 256;
        v[u] = we[(long)id * H_ + i] + pe[s * H_ + i] + te[i];
    }
    float sum = v[0] + v[1] + v[2];
    float ssq = v[0]*v[0] + v[1]*v[1] + v[2]*v[2];
    block_reduce2(sum, ssq);
    const float mean = sum * (1.0f / H_);
    const float var  = ssq * (1.0f / H_) - mean * mean;
    const float inv  = 1.0f / sqrtf(var + 1e-12f);
    #pragma unroll
    for (int u = 0; u < 3; ++u) {
        const int i = tid + u * 256;
        const float z = (v[u] - mean) * inv * g[i] + bb[i];
        out[row * H_ + i] = z;
        unsigned short h, l; split_bf16(z, h, l);
        ohi[row * H_ + i] = h; olo[row * H_ + i] = l;
    }
}

// ---------------------------------------------------------------------------
// Residual add + LayerNorm; writes fp32 + hi/lo bf16
// ---------------------------------------------------------------------------
__global__ __launch_bounds__(256) void resid_ln_kernel(
        const float* __restrict__ x, const float* __restrict__ y,
        const float* __restrict__ g, const float* __restrict__ bb,
        float* __restrict__ out, unsigned short* __restrict__ ohi,
        unsigned short* __restrict__ olo) {
    const int row = blockIdx.x;
    const int tid = threadIdx.x;
    float v[3];
    #pragma unroll
    for (int u = 0; u < 3; ++u) {
        const int i = tid + u * 256;
        v[u] = x[row * H_ + i] + y[row * H_ + i];
    }
    float sum = v[0] + v[1] + v[2];
    float ssq = v[0]*v[0] + v[1]*v[1] + v[2]*v[2];
    block_reduce2(sum, ssq);
    const float mean = sum * (1.0f / H_);
    const float var  = ssq * (1.0f / H_) - mean * mean;
    const float inv  = 1.0f / sqrtf(var + 1e-12f);
    #pragma unroll
    for (int u = 0; u < 3; ++u) {
        const int i = tid + u * 256;
        const float z = (v[u] - mean) * inv * g[i] + bb[i];
        out[row * H_ + i] = z;
        unsigned short h, l; split_bf16(z, h, l);
        ohi[row * H_ + i] = h; olo[row * H_ + i] = l;
    }
}

// ---------------------------------------------------------------------------
// Per-layer weight convert + transpose: W[K,N] fp32 -> WT[N,K] hi/lo bf16.
// One block per 64x64 tile; 1728 tiles cover Wq,Wk,Wv,Wo,W1,W2 of one layer.
// ---------------------------------------------------------------------------
__global__ __launch_bounds__(256) void wconvert_kernel(
        const float* __restrict__ Wq, const float* __restrict__ Wk,
        const float* __restrict__ Wv, const float* __restrict__ Wo,
        const float* __restrict__ W1, const float* __restrict__ W2,
        unsigned short* __restrict__ TH, unsigned short* __restrict__ TL) {
    __shared__ float tile[64][68];
    int idx = blockIdx.x;
    const float* W; long off; int K, N;
    if (idx < 576) {
        const int m = idx / 144; idx -= m * 144;
        if      (m == 0) W = Wq;
        else if (m == 1) W = Wk;
        else if (m == 2) W = Wv;
        else             W = Wo;
        off = (long)m * (H_ * H_); K = H_; N = H_;
    } else if (idx < 1152) {
        W = W1; off = OFF_1; K = H_; N = FF_; idx -= 576;
    } else {
        W = W2; off = OFF_2; K = FF_; N = H_; idx -= 1152;
    }
    const int ntn = N >> 6;
    const int by = idx / ntn, bx = idx - by * ntn;
    const int k0 = by * 64, n0 = bx * 64;
    const int tid = threadIdx.x;
    const int rr = tid >> 4, cc = (tid & 15) * 4;
    #pragma unroll
    for (int p = 0; p < 4; ++p) {
        const int k = rr + p * 16;
        const float4 v = *(const float4*)&W[(long)(k0 + k) * N + n0 + cc];
        tile[k][cc] = v.x; tile[k][cc+1] = v.y; tile[k][cc+2] = v.z; tile[k][cc+3] = v.w;
    }
    __syncthreads();
    const int nl = tid >> 2, q = (tid & 3) * 16;
    unsigned short* th = TH + off;
    unsigned short* tl = TL + off;
    #pragma unroll
    for (int j = 0; j < 4; ++j) {
        unsigned short h4[4], l4[4];
        #pragma unroll
        for (int e = 0; e < 4; ++e) split_bf16(tile[q + j*4 + e][nl], h4[e], l4[e]);
        *(ushort4*)&th[(long)(n0 + nl) * K + k0 + q + j*4] = make_ushort4(h4[0], h4[1], h4[2], h4[3]);
        *(ushort4*)&tl[(long)(n0 + nl) * K + k0 + q + j*4] = make_ushort4(l4[0], l4[1], l4[2], l4[3]);
    }
}

// ---------------------------------------------------------------------------
// MFMA bf16 GEMM v3, pre-split operands. C = A[M,K] @ B^T[N,K] + bias.
// A given as (Ahi,Alo) [M,K] bf16; B as (Bhi,Blo) [N,K] bf16 (pre-transposed).
// 3-pass split accumulate: hi*hi + hi*lo + lo*hi (fp32 MFMA, ~2^-17 rel err).
// Block 128x128, BK=32, 4 waves of 64x64 (4x4 frags 16x16x32).
// EPI==1: exact GELU. OUTHL==1: write hi/lo bf16 instead of fp32.
// ---------------------------------------------------------------------------
template <int EPI, int OUTHL>
__global__ __launch_bounds__(256) void gemm_bf16_kernel(
        const unsigned short* __restrict__ Ahi, const unsigned short* __restrict__ Alo,
        const unsigned short* __restrict__ Bhi, const unsigned short* __restrict__ Blo,
        const float* __restrict__ bias, float* __restrict__ C,
        unsigned short* __restrict__ Chi, unsigned short* __restrict__ Clo,
        int M, int N, int K) {
    __shared__ unsigned short As_hi[128 * 40];
    __shared__ unsigned short As_lo[128 * 40];
    __shared__ unsigned short Bs_hi[128 * 40];
    __shared__ unsigned short Bs_lo[128 * 40];

    const int tid  = threadIdx.x;
    const int lane = tid & 63;
    const int wid  = tid >> 6;
    const int row0 = blockIdx.y * 128;
    const int col0 = blockIdx.x * 128;
    const int wm = (wid >> 1) * 64;
    const int wn = (wid & 1) * 64;
    const int lr = lane & 15;
    const int lk = (lane >> 4) * 8;
    const int sr = tid >> 1;           // staging row 0..127
    const int sk = (tid & 1) * 16;     // staging k-offset (16 elems per thread)

    const unsigned short* Ahp = Ahi + (long)(row0 + sr) * K + sk;
    const unsigned short* Alp = Alo + (long)(row0 + sr) * K + sk;
    const unsigned short* Bhp = Bhi + (long)(col0 + sr) * K + sk;
    const unsigned short* Blp = Blo + (long)(col0 + sr) * K + sk;

    f32x4 acc[4][4];
    #pragma unroll
    for (int mi = 0; mi < 4; ++mi)
        #pragma unroll
        for (int nj = 0; nj < 4; ++nj)
            acc[mi][nj] = (f32x4)(0.0f);

    for (int k0 = 0; k0 < K; k0 += 32) {
        const u16x8 ah0 = *(const u16x8*)(Ahp + k0);
        const u16x8 ah1 = *(const u16x8*)(Ahp + k0 + 8);
        const u16x8 al0 = *(const u16x8*)(Alp + k0);
        const u16x8 al1 = *(const u16x8*)(Alp + k0 + 8);
        const u16x8 bh0 = *(const u16x8*)(Bhp + k0);
        const u16x8 bh1 = *(const u16x8*)(Bhp + k0 + 8);
        const u16x8 bl0 = *(const u16x8*)(Blp + k0);
        const u16x8 bl1 = *(const u16x8*)(Blp + k0 + 8);

        __syncthreads();   // previous iteration's fragment reads complete

        *(u16x8*)&As_hi[sr * 40 + sk]     = ah0;
        *(u16x8*)&As_hi[sr * 40 + sk + 8] = ah1;
        *(u16x8*)&As_lo[sr * 40 + sk]     = al0;
        *(u16x8*)&As_lo[sr * 40 + sk + 8] = al1;
        *(u16x8*)&Bs_hi[sr * 40 + sk]     = bh0;
        *(u16x8*)&Bs_hi[sr * 40 + sk + 8] = bh1;
        *(u16x8*)&Bs_lo[sr * 40 + sk]     = bl0;
        *(u16x8*)&Bs_lo[sr * 40 + sk + 8] = bl1;

        __syncthreads();   // tile staged

        bf16x8 af_h[4], af_l[4], bf_h[4], bf_l[4];
        #pragma unroll
        for (int mi = 0; mi < 4; ++mi) {
            af_h[mi] = *(const bf16x8*)&As_hi[(wm + mi * 16 + lr) * 40 + lk];
            af_l[mi] = *(const bf16x8*)&As_lo[(wm + mi * 16 + lr) * 40 + lk];
        }
        #pragma unroll
        for (int nj = 0; nj < 4; ++nj) {
            bf_h[nj] = *(const bf16x8*)&Bs_hi[(wn + nj * 16 + lr) * 40 + lk];
            bf_l[nj] = *(const bf16x8*)&Bs_lo[(wn + nj * 16 + lr) * 40 + lk];
        }
        #pragma unroll
        for (int mi = 0; mi < 4; ++mi)
            #pragma unroll
            for (int nj = 0; nj < 4; ++nj) {
                acc[mi][nj] = __builtin_amdgcn_mfma_f32_16x16x32_bf16(af_h[mi], bf_h[nj], acc[mi][nj], 0, 0, 0);
                acc[mi][nj] = __builtin_amdgcn_mfma_f32_16x16x32_bf16(af_h[mi], bf_l[nj], acc[mi][nj], 0, 0, 0);
                acc[mi][nj] = __builtin_amdgcn_mfma_f32_16x16x32_bf16(af_l[mi], bf_h[nj], acc[mi][nj], 0, 0, 0);
            }
    }

    // C/D layout: col = lane&15, row = (lane>>4)*4 + reg (m89-verified)
    #pragma unroll
    for (int nj = 0; nj < 4; ++nj) {
        const int col = col0 + wn + nj * 16 + lr;
        const float bval = bias[col];
        #pragma unroll
        for (int mi = 0; mi < 4; ++mi) {
            const int rowb = row0 + wm + mi * 16 + (lane >> 4) * 4;
            #pragma unroll
            for (int r = 0; r < 4; ++r) {
                float z = acc[mi][nj][r] + bval;
                if constexpr (EPI == 1) z = 0.5f * z * (1.0f + erff(z * 0.70710678118654752f));
                if constexpr (OUTHL == 1) {
                    unsigned short h, l; split_bf16(z, h, l);
                    Chi[(long)(rowb + r) * N + col] = h;
                    Clo[(long)(rowb + r) * N + col] = l;
                } else {
                    C[(long)(rowb + r) * N + col] = z;
                }
            }
        }
    }
}

// ---------------------------------------------------------------------------
// Fused attention: block = (b, head, q-tile of 64). 256 threads = 64 q x 4
// lanes; lane owns 16 dims. Writes ctx as hi/lo bf16 (feeds Wo GEMM only).
// ---------------------------------------------------------------------------
__global__ __launch_bounds__(256) void attn_kernel(
        const float* __restrict__ Q, const float* __restrict__ K,
        const float* __restrict__ V, unsigned short* __restrict__ Ohi,
        unsigned short* __restrict__ Olo) {
    const int blk = blockIdx.x;
    const int qt  = blk & 3;
    const int bh  = blk >> 2;
    const int b   = bh / NH_;
    const int h   = bh % NH_;
    const int tid = threadIdx.x;
    const int ql  = tid >> 2;
    const int d0  = (tid & 3) * 16;
    __shared__ float Ks[64][68];
    __shared__ float Vs[64][68];
    const long base = (long)(b * S_) * H_ + h * DH_;
    const int qrow = qt * 64 + ql;

    float qr[16];
    #pragma unroll
    for (int d4 = 0; d4 < 4; ++d4) {
        const float4 t = *(const float4*)&Q[base + (long)qrow * H_ + d0 + d4 * 4];
        qr[d4*4+0] = t.x * 0.125f; qr[d4*4+1] = t.y * 0.125f;
        qr[d4*4+2] = t.z * 0.125f; qr[d4*4+3] = t.w * 0.125f;
    }
    float acc[16] = {};
    float m_run = -1e30f, l_run = 0.0f;

    for (int kt = 0; kt < 4; ++kt) {
        __syncthreads();
        #pragma unroll
        for (int u = 0; u < 4; ++u) {
            const int idx = tid + u * 256;
            const int r = idx >> 4, c = (idx & 15) * 4;
            *(float4*)&Ks[r][c] = *(const float4*)&K[base + (long)(kt*64 + r) * H_ + c];
            *(float4*)&Vs[r][c] = *(const float4*)&V[base + (long)(kt*64 + r) * H_ + c];
        }
        __syncthreads();
        for (int ch = 0; ch < 4; ++ch) {
            float sreg[16];
            float mx = -1e30f;
            #pragma unroll
            for (int jj = 0; jj < 16; ++jj) {
                const int j = ch * 16 + jj;
                float a = 0.0f;
                #pragma unroll
                for (int d4 = 0; d4 < 4; ++d4) {
                    const float4 kv = *(const float4*)&Ks[j][d0 + d4 * 4];
                    a += qr[d4*4+0]*kv.x + qr[d4*4+1]*kv.y
                       + qr[d4*4+2]*kv.z + qr[d4*4+3]*kv.w;
                }
                a += __shfl_xor(a, 1);
                a += __shfl_xor(a, 2);
                sreg[jj] = a;
                mx = fmaxf(mx, a);
            }
            const float m_new = fmaxf(m_run, mx);
            const float corr  = __expf(m_run - m_new);
            l_run *= corr;
            #pragma unroll
            for (int d = 0; d < 16; ++d) acc[d] *= corr;
            #pragma unroll
            for (int jj = 0; jj < 16; ++jj) {
                const float p = __expf(sreg[jj] - m_new);
                l_run += p;
                const int j = ch * 16 + jj;
                #pragma unroll
                for (int d4 = 0; d4 < 4; ++d4) {
                    const float4 vv = *(const float4*)&Vs[j][d0 + d4 * 4];
                    acc[d4*4+0] += p * vv.x; acc[d4*4+1] += p * vv.y;
                    acc[d4*4+2] += p * vv.z; acc[d4*4+3] += p * vv.w;
                }
            }
            m_run = m_new;
        }
    }
    const float inv = 1.0f / l_run;
    #pragma unroll
    for (int d4 = 0; d4 < 4; ++d4) {
        unsigned short h4[4], l4[4];
        #pragma unroll
        for (int e = 0; e < 4; ++e) split_bf16(acc[d4*4+e] * inv, h4[e], l4[e]);
        const long o = base + (long)qrow * H_ + d0 + d4 * 4;
        *(ushort4*)&Ohi[o] = make_ushort4(h4[0], h4[1], h4[2], h4[3]);
        *(ushort4*)&Olo[o] = make_ushort4(l4[0], l4[1], l4[2], l4[3]);
    }
}

// ---------------------------------------------------------------------------
// Final FC: feats[row, 0..8] = x[row,:] @ fc_w + fc_b  (one wave per row)
// ---------------------------------------------------------------------------
__global__ __launch_bounds__(64) void fc_kernel(
        const float* __restrict__ x, const float* __restrict__ w,
        const float* __restrict__ wb, float* __restrict__ feats) {
    const int row  = blockIdx.x;
    const int lane = threadIdx.x;
    float acc[NT_] = {};
    for (int i = lane; i < H_; i += 64) {
        const float xv = x[(long)row * H_ + i];
        #pragma unroll
        for (int t = 0; t < NT_; ++t) acc[t] += xv * w[i * NT_ + t];
    }
    #pragma unroll
    for (int t = 0; t < NT_; ++t) {
        #pragma unroll
        for (int off = 32; off; off >>= 1) acc[t] += __shfl_down(acc[t], off);
    }
    if (lane == 0) {
        #pragma unroll
        for (int t = 0; t < NT_; ++t) feats[row * NT_ + t] = acc[t] + wb[t];
    }
}

// ---------------------------------------------------------------------------
// Viterbi: single block. Forward 254 steps, then backtrack.
// ---------------------------------------------------------------------------
__global__ __launch_bounds__(128) void viterbi_kernel(
        const float* __restrict__ feats, const float* __restrict__ trans,
        float* __restrict__ out, int* __restrict__ bps) {
    __shared__ float fv[B_][NT_];
    __shared__ float fvn[B_][NT_];
    __shared__ float tr[NT_ * NT_];
    const int tid = threadIdx.x;
    if (tid < NT_ * NT_) tr[tid] = trans[tid];
    if (tid < B_ * NT_) {
        const int b = tid / NT_, i = tid % NT_;
        fv[b][i] = (i == 7) ? 0.0f : NEG_;
    }
    __syncthreads();
    for (int t = 0; t < TLEN_; ++t) {
        if (tid < B_ * NT_) {
            const int b = tid / NT_, i = tid % NT_;
            float best = fv[b][0] + tr[i * NT_ + 0];
            int bj = 0;
            #pragma unroll
            for (int j = 1; j < NT_; ++j) {
                const float c = fv[b][j] + tr[i * NT_ + j];
                if (c > best) { best = c; bj = j; }
            }
            bps[(t * B_ + b) * NT_ + i] = bj;
            fvn[b][i] = best + feats[((b * S_) + 1 + t) * NT_ + i];
        }
        __syncthreads();
        if (tid < B_ * NT_) {
            const int b = tid / NT_, i = tid % NT_;
            fv[b][i] = fvn[b][i];
        }
        __syncthreads();
    }
    if (tid < B_) {
        const int b = tid;
        float best = fv[b][0] + tr[8 * NT_ + 0];
        int bi = 0;
        #pragma unroll
        for (int i = 1; i < NT_; ++i) {
            const float c = fv[b][i] + tr[8 * NT_ + i];
            if (c > best) { best = c; bi = i; }
        }
        out[b] = best;
        float* path = out + B_ + b * TLEN_;
        int tag = bi;
        path[TLEN_ - 1] = (float)tag;
        for (int t = TLEN_ - 2; t >= 0; --t) {
            tag = bps[((t + 1) * B_ + b) * NT_ + tag];
            path[t] = (float)tag;
        }
    }
}

// ---------------------------------------------------------------------------
// Host orchestration
// ---------------------------------------------------------------------------
extern "C" void kernel_launch(void* const* d_in, const int* in_sizes, int n_in,
                              void* d_out, int out_size, void* d_ws, size_t ws_size,
                              hipStream_t stream) {
    const int*   sentences = (const int*)  d_in[0];
    const float* word_emb  = (const float*)d_in[2];
    const float* pos_emb   = (const float*)d_in[3];
    const float* type_emb  = (const float*)d_in[4];
    const float* emb_ln_s  = (const float*)d_in[5];
    const float* emb_ln_b  = (const float*)d_in[6];
    const float* Wq = (const float*)d_in[7];
    const float* bq = (const float*)d_in[8];
    const float* Wk = (const float*)d_in[9];
    const float* bk = (const float*)d_in[10];
    const float* Wv = (const float*)d_in[11];
    const float* bv = (const float*)d_in[12];
    const float* Wo = (const float*)d_in[13];
    const float* bo = (const float*)d_in[14];
    const float* ln1_s = (const float*)d_in[15];
    const float* ln1_b = (const float*)d_in[16];
    const float* W1 = (const float*)d_in[17];
    const float* b1 = (const float*)d_in[18];
    const float* W2 = (const float*)d_in[19];
    const float* b2 = (const float*)d_in[20];
    const float* ln2_s = (const float*)d_in[21];
    const float* ln2_b = (const float*)d_in[22];
    const float* fc_w  = (const float*)d_in[23];
    const float* fc_b  = (const float*)d_in[24];
    const float* transitions = (const float*)d_in[25];

    const long NTOKH = (long)TOK_ * H_;        // 1,572,864
    const long NTOKF = (long)TOK_ * FF_;       // 6,291,456

    float* wsf  = (float*)d_ws;
    float* x    = wsf;                 // fp32 residual stream
    float* q    = x + NTOKH;
    float* kbuf = q + NTOKH;
    float* vbuf = kbuf + NTOKH;
    unsigned short* xhi   = (unsigned short*)(vbuf + NTOKH);
    unsigned short* xlo   = xhi + NTOKH;       // also reused for ctx hi/lo
    unsigned short* ffhhi = xlo + NTOKH;
    unsigned short* ffhlo = ffhhi + NTOKF;
    unsigned short* wthi  = ffhlo + NTOKF;
    unsigned short* wtlo  = wthi + WTOT_;
    float* feats = (float*)(wtlo + WTOT_);
    int*   bps   = (int*)(feats + (long)TOK_ * NT_);

    embed_ln_kernel<<<TOK_, 256, 0, stream>>>(sentences, word_emb, pos_emb,
                                              type_emb, emb_ln_s, emb_ln_b,
                                              x, xhi, xlo);

    const dim3 gH(H_ / 128, TOK_ / 128);    // 6 x 16  (N=768)
    const dim3 gF(FF_ / 128, TOK_ / 128);   // 24 x 16 (N=3072)

    for (int l = 0; l < NL_; ++l) {
        wconvert_kernel<<<1728, 256, 0, stream>>>(
            Wq + (long)l * H_ * H_, Wk + (long)l * H_ * H_,
            Wv + (long)l * H_ * H_, Wo + (long)l * H_ * H_,
            W1 + (long)l * H_ * FF_, W2 + (long)l * FF_ * H_,
            wthi, wtlo);

        gemm_bf16_kernel<0,0><<<gH, 256, 0, stream>>>(
            xhi, xlo, wthi + OFF_Q, wtlo + OFF_Q, bq + l * H_,
            q, nullptr, nullptr, TOK_, H_, H_);
        gemm_bf16_kernel<0,0><<<gH, 256, 0, stream>>>(
            xhi, xlo, wthi + OFF_K, wtlo + OFF_K, bk + l * H_,
            kbuf, nullptr, nullptr, TOK_, H_, H_);
        gemm_bf16_kernel<0,0><<<gH, 256, 0, stream>>>(
            xhi, xlo, wthi + OFF_V, wtlo + OFF_V, bv + l * H_,
            vbuf, nullptr, nullptr, TOK_, H_, H_);

        // ctx -> xhi/xlo (QKV GEMMs already consumed the old xhi/xlo)
        attn_kernel<<<B_ * NH_ * 4, 256, 0, stream>>>(q, kbuf, vbuf, xhi, xlo);

        gemm_bf16_kernel<0,0><<<gH, 256, 0, stream>>>(
            xhi, xlo, wthi + OFF_O, wtlo + OFF_O, bo + l * H_,
            kbuf, nullptr, nullptr, TOK_, H_, H_);
        resid_ln_kernel<<<TOK_, 256, 0, stream>>>(x, kbuf, ln1_s + l * H_, ln1_b + l * H_,
                                                  x, xhi, xlo);

        gemm_bf16_kernel<1,1><<<gF, 256, 0, stream>>>(
            xhi, xlo, wthi + OFF_1, wtlo + OFF_1, b1 + l * FF_,
            nullptr, ffhhi, ffhlo, TOK_, FF_, H_);
        gemm_bf16_kernel<0,0><<<gH, 256, 0, stream>>>(
            ffhhi, ffhlo, wthi + OFF_2, wtlo + OFF_2, b2 + l * H_,
            kbuf, nullptr, nullptr, TOK_, H_, FF_);
        resid_ln_kernel<<<TOK_, 256, 0, stream>>>(x, kbuf, ln2_s + l * H_, ln2_b + l * H_,
                                                  x, xhi, xlo);
    }

    fc_kernel<<<TOK_, 64, 0, stream>>>(x, fc_w, fc_b, feats);
    viterbi_kernel<<<1, 128, 0, stream>>>(feats, transitions, (float*)d_out, bps);
}